// Round 1
// baseline (531.347 us; speedup 1.0000x reference)
//
#include <hip/hip_runtime.h>
#include <cfloat>

#define M_UP   32768
#define N_DOWN 8192
#define UPC    128
#define DOWNC  256
#define OUTC   128
#define NCHUNK 4
#define CHUNK  (N_DOWN / NCHUNK)   // 2048

__device__ __forceinline__ void fma4(float4& acc, float s, const float4 w) {
    acc.x = fmaf(s, w.x, acc.x);
    acc.y = fmaf(s, w.y, acc.y);
    acc.z = fmaf(s, w.z, acc.z);
    acc.w = fmaf(s, w.w, acc.w);
}

__device__ __forceinline__ void top3_insert(float s, int gi,
                                            float& d0, float& d1, float& d2,
                                            int& i0, int& i1, int& i2) {
    // strict < everywhere => stable (earlier-scanned index wins ties), matching
    // jax.lax.top_k's lower-index-first tie-break when scanned in index order.
    if (s < d1) {
        d2 = d1; i2 = i1;
        if (s < d0) { d1 = d0; i1 = i0; d0 = s; i0 = gi; }
        else        { d1 = s;  i1 = gi; }
    } else {
        d2 = s; i2 = gi;
    }
}

// ---------------------------------------------------------------------------
// K0: transpose W_down [128,256] -> wt_down [256,128] and W_up [128,128] ->
// wt_up [128,128] so GEMM kernels can read W with coalesced float4 loads.
// ---------------------------------------------------------------------------
__global__ __launch_bounds__(256) void transpose_w(
        const float* __restrict__ W_up, const float* __restrict__ W_down,
        float* __restrict__ wt_up, float* __restrict__ wt_down) {
    int e = blockIdx.x * 256 + threadIdx.x;   // grid covers 32768 + 16384 exactly
    if (e < DOWNC * OUTC) {
        int k = e >> 7, c = e & 127;          // wt_down[k][c] = W_down[c][k]
        wt_down[e] = W_down[c * DOWNC + k];
    } else {
        int e2 = e - DOWNC * OUTC;
        int k = e2 >> 7, c = e2 & 127;        // wt_up[k][c] = W_up[c][k]
        wt_up[e2] = W_up[c * UPC + k];
    }
}

// ---------------------------------------------------------------------------
// K1: down_f[n][c] = down_features[n][:] @ W_down.T + b_down  (8192 x 128)
// Block: 256 threads = 32 c4-groups x 8 row-pairs; 16 rows/block, 512 blocks.
// No LDS: A rows via float4 (L1-hot), wt_down streamed coalesced from L2.
// ---------------------------------------------------------------------------
__global__ __launch_bounds__(256) void down_proj(
        const float* __restrict__ A,        // down_features [8192][256]
        const float* __restrict__ WT,       // wt_down [256][128]
        const float* __restrict__ bias,     // b_down [128]
        float* __restrict__ down_f) {       // [8192][128]
    const int c4 = threadIdx.x & 31;
    const int rr = threadIdx.x >> 5;        // 0..7
    const int r0 = blockIdx.x * 16 + rr;
    const int r1 = r0 + 8;
    const float* A0 = A + r0 * DOWNC;
    const float* A1 = A + r1 * DOWNC;
    float4 acc0 = {0.f, 0.f, 0.f, 0.f};
    float4 acc1 = {0.f, 0.f, 0.f, 0.f};
    for (int k = 0; k < DOWNC; k += 4) {
        float4 a0 = *(const float4*)(A0 + k);
        float4 a1 = *(const float4*)(A1 + k);
        const float4* wp = (const float4*)(WT + k * OUTC) + c4;
        float4 w0 = wp[0], w1 = wp[32], w2 = wp[64], w3 = wp[96];
        fma4(acc0, a0.x, w0); fma4(acc0, a0.y, w1);
        fma4(acc0, a0.z, w2); fma4(acc0, a0.w, w3);
        fma4(acc1, a1.x, w0); fma4(acc1, a1.y, w1);
        fma4(acc1, a1.z, w2); fma4(acc1, a1.w, w3);
    }
    float4 b = ((const float4*)bias)[c4];
    acc0.x += b.x; acc0.y += b.y; acc0.z += b.z; acc0.w += b.w;
    acc1.x += b.x; acc1.y += b.y; acc1.z += b.z; acc1.w += b.w;
    ((float4*)down_f)[r0 * 32 + c4] = acc0;
    ((float4*)down_f)[r1 * 32 + c4] = acc1;
}

// ---------------------------------------------------------------------------
// K2: brute-force partial 3-NN. Grid (128 query-blocks, 4 chunks); each thread
// owns one query and scans 2048 down points staged in LDS (broadcast reads).
// Writes per-chunk sorted top-3 (dist, global idx) to workspace.
// ---------------------------------------------------------------------------
__global__ __launch_bounds__(256) void knn_partial(
        const float* __restrict__ up_points,    // [32768][3]
        const float* __restrict__ down_points,  // [8192][3]
        float* __restrict__ part_d,             // [4][32768][3]
        int* __restrict__ part_i) {             // [4][32768][3]
    __shared__ float4 spts[CHUNK];              // 32 KB
    const int base = blockIdx.y * CHUNK;
    for (int t = threadIdx.x; t < CHUNK; t += 256) {
        int g = base + t;
        spts[t] = make_float4(down_points[3 * g], down_points[3 * g + 1],
                              down_points[3 * g + 2], 0.f);
    }
    __syncthreads();
    const int m = blockIdx.x * 256 + threadIdx.x;
    const float qx = up_points[3 * m];
    const float qy = up_points[3 * m + 1];
    const float qz = up_points[3 * m + 2];
    float d0 = FLT_MAX, d1 = FLT_MAX, d2 = FLT_MAX;
    int i0 = 0, i1 = 0, i2 = 0;
    #pragma unroll 8
    for (int i = 0; i < CHUNK; ++i) {
        float4 p = spts[i];
        float dx = qx - p.x, dy = qy - p.y, dz = qz - p.z;
        float s = fmaf(dz, dz, fmaf(dy, dy, dx * dx));
        if (s < d2) {   // rare after warm-up; branch beats branchless here
            top3_insert(s, base + i, d0, d1, d2, i0, i1, i2);
        }
    }
    const int o = (blockIdx.y * M_UP + m) * 3;
    part_d[o] = d0; part_d[o + 1] = d1; part_d[o + 2] = d2;
    part_i[o] = i0; part_i[o + 1] = i1; part_i[o + 2] = i2;
}

// ---------------------------------------------------------------------------
// K3: fused up-projection GEMM + top-3 merge + inverse-distance interpolation
// + bias + output. Same no-LDS GEMM structure as K1 (16 rows/block, 2048 blks).
// ---------------------------------------------------------------------------
__global__ __launch_bounds__(256) void up_fused(
        const float* __restrict__ A,        // up_features [32768][128]
        const float* __restrict__ WT,       // wt_up [128][128]
        const float* __restrict__ bias,     // b_up [128]
        const float* __restrict__ down_f,   // [8192][128]
        const float* __restrict__ part_d,
        const int* __restrict__ part_i,
        float* __restrict__ out) {          // [32768][128]
    const int c4 = threadIdx.x & 31;
    const int rr = threadIdx.x >> 5;
    const int q0 = blockIdx.x * 16 + rr;
    const int q1 = q0 + 8;
    const float* A0 = A + q0 * UPC;
    const float* A1 = A + q1 * UPC;
    float4 acc0 = {0.f, 0.f, 0.f, 0.f};
    float4 acc1 = {0.f, 0.f, 0.f, 0.f};
    for (int k = 0; k < UPC; k += 4) {
        float4 a0 = *(const float4*)(A0 + k);
        float4 a1 = *(const float4*)(A1 + k);
        const float4* wp = (const float4*)(WT + k * OUTC) + c4;
        float4 w0 = wp[0], w1 = wp[32], w2 = wp[64], w3 = wp[96];
        fma4(acc0, a0.x, w0); fma4(acc0, a0.y, w1);
        fma4(acc0, a0.z, w2); fma4(acc0, a0.w, w3);
        fma4(acc1, a1.x, w0); fma4(acc1, a1.y, w1);
        fma4(acc1, a1.z, w2); fma4(acc1, a1.w, w3);
    }
    const float4 b = ((const float4*)bias)[c4];
    const float4* df4 = (const float4*)down_f;
    #pragma unroll
    for (int t = 0; t < 2; ++t) {
        const int q = t ? q1 : q0;
        float4 acc = t ? acc1 : acc0;
        // merge 4 chunk-wise sorted top-3 lists, scanned in ascending global
        // index order with strict compares => identical tie-break to top_k.
        float D0 = FLT_MAX, D1 = FLT_MAX, D2 = FLT_MAX;
        int I0 = 0, I1 = 0, I2 = 0;
        #pragma unroll
        for (int s = 0; s < NCHUNK; ++s) {
            const int o = (s * M_UP + q) * 3;
            #pragma unroll
            for (int j = 0; j < 3; ++j) {
                float d = part_d[o + j];
                int gi = part_i[o + j];
                if (d < D2) top3_insert(d, gi, D0, D1, D2, I0, I1, I2);
            }
        }
        // weights exactly as reference: recip = 1/(d+1e-8); w = recip/sum
        float r0 = 1.f / (D0 + 1e-8f);
        float r1 = 1.f / (D1 + 1e-8f);
        float r2 = 1.f / (D2 + 1e-8f);
        float rs = (r0 + r1) + r2;
        float w0 = r0 / rs, w1 = r1 / rs, w2 = r2 / rs;
        float4 f0 = df4[I0 * 32 + c4];
        float4 f1 = df4[I1 * 32 + c4];
        float4 f2 = df4[I2 * 32 + c4];
        float4 res;
        res.x = acc.x + b.x + fmaf(w0, f0.x, fmaf(w1, f1.x, w2 * f2.x));
        res.y = acc.y + b.y + fmaf(w0, f0.y, fmaf(w1, f1.y, w2 * f2.y));
        res.z = acc.z + b.z + fmaf(w0, f0.z, fmaf(w1, f1.z, w2 * f2.z));
        res.w = acc.w + b.w + fmaf(w0, f0.w, fmaf(w1, f1.w, w2 * f2.w));
        ((float4*)out)[q * 32 + c4] = res;
    }
}

extern "C" void kernel_launch(void* const* d_in, const int* in_sizes, int n_in,
                              void* d_out, int out_size, void* d_ws, size_t ws_size,
                              hipStream_t stream) {
    const float* up_points     = (const float*)d_in[0];   // [32768,3]
    const float* up_features   = (const float*)d_in[1];   // [32768,128]
    const float* down_points   = (const float*)d_in[2];   // [8192,3]
    const float* down_features = (const float*)d_in[3];   // [8192,256]
    const float* W_up          = (const float*)d_in[4];   // [128,128]
    const float* b_up          = (const float*)d_in[5];   // [128]
    const float* W_down        = (const float*)d_in[6];   // [128,256]
    const float* b_down        = (const float*)d_in[7];   // [128]
    float* out = (float*)d_out;

    // workspace layout (floats): wt_down | wt_up | down_f | part_d | part_i
    float* wt_down = (float*)d_ws;                         // 256*128
    float* wt_up   = wt_down + DOWNC * OUTC;               // 128*128
    float* down_f  = wt_up + UPC * OUTC;                   // 8192*128
    float* part_d  = down_f + N_DOWN * OUTC;               // 4*32768*3
    int*   part_i  = (int*)(part_d + NCHUNK * M_UP * 3);   // 4*32768*3
    // total ~7.2 MB

    transpose_w<<<(DOWNC * OUTC + UPC * OUTC) / 256, 256, 0, stream>>>(
        W_up, W_down, wt_up, wt_down);
    down_proj<<<N_DOWN / 16, 256, 0, stream>>>(
        down_features, wt_down, b_down, down_f);
    knn_partial<<<dim3(M_UP / 256, NCHUNK), 256, 0, stream>>>(
        up_points, down_points, part_d, part_i);
    up_fused<<<M_UP / 16, 256, 0, stream>>>(
        up_features, wt_up, b_up, down_f, part_d, part_i, out);
}

// Round 2
// 252.721 us; speedup vs baseline: 2.1025x; 2.1025x over previous
//
#include <hip/hip_runtime.h>
#include <cfloat>

#define M_UP   32768
#define N_DOWN 8192
#define UPC    128
#define DOWNC  256
#define OUTC   128
#define NCHUNK 8
#define CHUNK  (N_DOWN / NCHUNK)   // 1024
#define G      8                   // selection group size

__device__ __forceinline__ void fma4(float4& acc, float s, const float4 w) {
    acc.x = fmaf(s, w.x, acc.x);
    acc.y = fmaf(s, w.y, acc.y);
    acc.z = fmaf(s, w.z, acc.z);
    acc.w = fmaf(s, w.w, acc.w);
}

// Branchless stable top-3 insert with index tracking.
// Strict < everywhere => earlier-inserted wins ties (stable in scan order),
// matching jax.lax.top_k's lower-index-first tie-break.
__device__ __forceinline__ void top3_bl(float s, int idx,
                                        float& d0, float& d1, float& d2,
                                        int& i0, int& i1, int& i2) {
    bool c0 = s < d0, c1 = s < d1, c2 = s < d2;
    float n0 = fminf(d0, s);
    float n1 = __builtin_amdgcn_fmed3f(d0, d1, s);
    float n2 = __builtin_amdgcn_fmed3f(d1, d2, s);
    int m0 = c0 ? idx : i0;
    int m1 = c0 ? i0 : (c1 ? idx : i1);
    int m2 = c1 ? i1 : (c2 ? idx : i2);
    d0 = n0; d1 = n1; d2 = n2;
    i0 = m0; i1 = m1; i2 = m2;
}

// ---------------------------------------------------------------------------
// K0: transpose weights for coalesced float4 GEMM reads.
// ---------------------------------------------------------------------------
__global__ __launch_bounds__(256) void transpose_w(
        const float* __restrict__ W_up, const float* __restrict__ W_down,
        float* __restrict__ wt_up, float* __restrict__ wt_down) {
    int e = blockIdx.x * 256 + threadIdx.x;
    if (e < DOWNC * OUTC) {
        int k = e >> 7, c = e & 127;
        wt_down[e] = W_down[c * DOWNC + k];
    } else {
        int e2 = e - DOWNC * OUTC;
        int k = e2 >> 7, c = e2 & 127;
        wt_up[e2] = W_up[c * UPC + k];
    }
}

// ---------------------------------------------------------------------------
// K1: down_f = down_features @ W_down.T + b_down  (8192 x 128)
// ---------------------------------------------------------------------------
__global__ __launch_bounds__(256) void down_proj(
        const float* __restrict__ A, const float* __restrict__ WT,
        const float* __restrict__ bias, float* __restrict__ down_f) {
    const int c4 = threadIdx.x & 31;
    const int rr = threadIdx.x >> 5;
    const int r0 = blockIdx.x * 16 + rr;
    const int r1 = r0 + 8;
    const float* A0 = A + r0 * DOWNC;
    const float* A1 = A + r1 * DOWNC;
    float4 acc0 = {0.f, 0.f, 0.f, 0.f};
    float4 acc1 = {0.f, 0.f, 0.f, 0.f};
    for (int k = 0; k < DOWNC; k += 4) {
        float4 a0 = *(const float4*)(A0 + k);
        float4 a1 = *(const float4*)(A1 + k);
        const float4* wp = (const float4*)(WT + k * OUTC) + c4;
        float4 w0 = wp[0], w1 = wp[32], w2 = wp[64], w3 = wp[96];
        fma4(acc0, a0.x, w0); fma4(acc0, a0.y, w1);
        fma4(acc0, a0.z, w2); fma4(acc0, a0.w, w3);
        fma4(acc1, a1.x, w0); fma4(acc1, a1.y, w1);
        fma4(acc1, a1.z, w2); fma4(acc1, a1.w, w3);
    }
    float4 b = ((const float4*)bias)[c4];
    acc0.x += b.x; acc0.y += b.y; acc0.z += b.z; acc0.w += b.w;
    acc1.x += b.x; acc1.y += b.y; acc1.z += b.z; acc1.w += b.w;
    ((float4*)down_f)[r0 * 32 + c4] = acc0;
    ((float4*)down_f)[r1 * 32 + c4] = acc1;
}

// ---------------------------------------------------------------------------
// K2: partial 3-NN, branchless grouped selection.
// Per thread: 1 query, scan CHUNK points in groups of G. Track top-3 groups
// by group-min (3 min/med3 + 3 cmp + 5 cndmask per group), then exactly
// refine the <=3 winning groups. Any group with min < true-d2 must contain
// a top-2 point, so <=3 groups can precede the group holding the true 3rd
// neighbor => the winners provably contain the exact top-3.
// ---------------------------------------------------------------------------
__global__ __launch_bounds__(256) void knn_partial(
        const float* __restrict__ up_points,
        const float* __restrict__ down_points,
        float* __restrict__ part_d,             // [NCHUNK][M_UP][3]
        int* __restrict__ part_i) {
    __shared__ float4 spts[CHUNK];              // 16 KB
    const int base = blockIdx.y * CHUNK;
    for (int t = threadIdx.x; t < CHUNK; t += 256) {
        int g = base + t;
        spts[t] = make_float4(down_points[3 * g], down_points[3 * g + 1],
                              down_points[3 * g + 2], 0.f);
    }
    __syncthreads();
    const int m = blockIdx.x * 256 + threadIdx.x;
    const float qx = up_points[3 * m];
    const float qy = up_points[3 * m + 1];
    const float qz = up_points[3 * m + 2];

    float gd0 = FLT_MAX, gd1 = FLT_MAX, gd2 = FLT_MAX;
    int gi0 = 0, gi1 = 0, gi2 = 0;
    for (int g = 0; g < CHUNK; g += G) {
        float s[G];
        #pragma unroll
        for (int j = 0; j < G; ++j) {
            float4 p = spts[g + j];
            float dx = qx - p.x, dy = qy - p.y, dz = qz - p.z;
            s[j] = fmaf(dz, dz, fmaf(dy, dy, dx * dx));
        }
        float m01 = fminf(s[0], s[1]), m23 = fminf(s[2], s[3]);
        float m45 = fminf(s[4], s[5]), m67 = fminf(s[6], s[7]);
        float gmin = fminf(fminf(m01, m23), fminf(m45, m67));
        top3_bl(gmin, g, gd0, gd1, gd2, gi0, gi1, gi2);
    }

    // exact refine over the 3 winning groups (24 points)
    float D0 = FLT_MAX, D1 = FLT_MAX, D2 = FLT_MAX;
    int I0 = 0, I1 = 0, I2 = 0;
    int bases[3] = {gi0, gi1, gi2};
    #pragma unroll
    for (int t = 0; t < 3; ++t) {
        const int b = bases[t];
        #pragma unroll
        for (int j = 0; j < G; ++j) {
            float4 p = spts[b + j];
            float dx = qx - p.x, dy = qy - p.y, dz = qz - p.z;
            float s = fmaf(dz, dz, fmaf(dy, dy, dx * dx));
            top3_bl(s, base + b + j, D0, D1, D2, I0, I1, I2);
        }
    }
    const int o = (blockIdx.y * M_UP + m) * 3;
    part_d[o] = D0; part_d[o + 1] = D1; part_d[o + 2] = D2;
    part_i[o] = I0; part_i[o + 1] = I1; part_i[o + 2] = I2;
}

// ---------------------------------------------------------------------------
// K3: fused up-projection + top-3 merge + interpolation + bias + add.
// ---------------------------------------------------------------------------
__global__ __launch_bounds__(256) void up_fused(
        const float* __restrict__ A, const float* __restrict__ WT,
        const float* __restrict__ bias, const float* __restrict__ down_f,
        const float* __restrict__ part_d, const int* __restrict__ part_i,
        float* __restrict__ out) {
    const int c4 = threadIdx.x & 31;
    const int rr = threadIdx.x >> 5;
    const int q0 = blockIdx.x * 16 + rr;
    const int q1 = q0 + 8;
    const float* A0 = A + q0 * UPC;
    const float* A1 = A + q1 * UPC;
    float4 acc0 = {0.f, 0.f, 0.f, 0.f};
    float4 acc1 = {0.f, 0.f, 0.f, 0.f};
    for (int k = 0; k < UPC; k += 4) {
        float4 a0 = *(const float4*)(A0 + k);
        float4 a1 = *(const float4*)(A1 + k);
        const float4* wp = (const float4*)(WT + k * OUTC) + c4;
        float4 w0 = wp[0], w1 = wp[32], w2 = wp[64], w3 = wp[96];
        fma4(acc0, a0.x, w0); fma4(acc0, a0.y, w1);
        fma4(acc0, a0.z, w2); fma4(acc0, a0.w, w3);
        fma4(acc1, a1.x, w0); fma4(acc1, a1.y, w1);
        fma4(acc1, a1.z, w2); fma4(acc1, a1.w, w3);
    }
    const float4 b = ((const float4*)bias)[c4];
    const float4* df4 = (const float4*)down_f;
    #pragma unroll
    for (int t = 0; t < 2; ++t) {
        const int q = t ? q1 : q0;
        float4 acc = t ? acc1 : acc0;
        float D0 = FLT_MAX, D1 = FLT_MAX, D2 = FLT_MAX;
        int I0 = 0, I1 = 0, I2 = 0;
        #pragma unroll
        for (int s = 0; s < NCHUNK; ++s) {
            const int o = (s * M_UP + q) * 3;
            #pragma unroll
            for (int j = 0; j < 3; ++j) {
                float d = part_d[o + j];
                int gi = part_i[o + j];
                top3_bl(d, gi, D0, D1, D2, I0, I1, I2);
            }
        }
        float r0 = 1.f / (D0 + 1e-8f);
        float r1 = 1.f / (D1 + 1e-8f);
        float r2 = 1.f / (D2 + 1e-8f);
        float rs = (r0 + r1) + r2;
        float w0 = r0 / rs, w1 = r1 / rs, w2 = r2 / rs;
        float4 f0 = df4[I0 * 32 + c4];
        float4 f1 = df4[I1 * 32 + c4];
        float4 f2 = df4[I2 * 32 + c4];
        float4 res;
        res.x = acc.x + b.x + fmaf(w0, f0.x, fmaf(w1, f1.x, w2 * f2.x));
        res.y = acc.y + b.y + fmaf(w0, f0.y, fmaf(w1, f1.y, w2 * f2.y));
        res.z = acc.z + b.z + fmaf(w0, f0.z, fmaf(w1, f1.z, w2 * f2.z));
        res.w = acc.w + b.w + fmaf(w0, f0.w, fmaf(w1, f1.w, w2 * f2.w));
        ((float4*)out)[q * 32 + c4] = res;
    }
}

extern "C" void kernel_launch(void* const* d_in, const int* in_sizes, int n_in,
                              void* d_out, int out_size, void* d_ws, size_t ws_size,
                              hipStream_t stream) {
    const float* up_points     = (const float*)d_in[0];
    const float* up_features   = (const float*)d_in[1];
    const float* down_points   = (const float*)d_in[2];
    const float* down_features = (const float*)d_in[3];
    const float* W_up          = (const float*)d_in[4];
    const float* b_up          = (const float*)d_in[5];
    const float* W_down        = (const float*)d_in[6];
    const float* b_down        = (const float*)d_in[7];
    float* out = (float*)d_out;

    float* wt_down = (float*)d_ws;                         // 256*128
    float* wt_up   = wt_down + DOWNC * OUTC;               // 128*128
    float* down_f  = wt_up + UPC * OUTC;                   // 8192*128
    float* part_d  = down_f + N_DOWN * OUTC;               // NCHUNK*32768*3
    int*   part_i  = (int*)(part_d + NCHUNK * M_UP * 3);   // NCHUNK*32768*3
    // total ~10.7 MB

    transpose_w<<<(DOWNC * OUTC + UPC * OUTC) / 256, 256, 0, stream>>>(
        W_up, W_down, wt_up, wt_down);
    down_proj<<<N_DOWN / 16, 256, 0, stream>>>(
        down_features, wt_down, b_down, down_f);
    knn_partial<<<dim3(M_UP / 256, NCHUNK), 256, 0, stream>>>(
        up_points, down_points, part_d, part_i);
    up_fused<<<M_UP / 16, 256, 0, stream>>>(
        up_features, wt_up, b_up, down_f, part_d, part_i, out);
}